// Round 5
// baseline (217.359 us; speedup 1.0000x reference)
//
#include <hip/hip_runtime.h>
#include <math.h>

// SNN event model: causal conv (K=8) + LIF scan + outputs (I, z, s, logits).
// Layout: x (32,1,8192) f32, conv_w (64,1,8) f32, raw_tau (64,) f32.
// out = [I (32*64*8192), z (same), s (same), logits (32*8192)] fp32.
//
// Block = 1 wave (lane = feature), grid = (chunk, batch); warm-up WARM steps.
//
// Ledger: R1 no-barrier: neutral. R2 occupancy 2->4 waves/SIMD: neutral per
// step (time tracks step count). R4 fp64->fp32: neutral. => kernel (~86 us)
// is ~85% stalled; invariant = per-tile serial structure.
// R5: store ONLY vp per tile (I/z/s reconstructed at flush:
//     I=(vp-a*v_prev)*inv_oma, v_prev=vp_prev<THR?vp_prev:0, z=15vp-3.75,
//     s=vp>=THR). Halves tile LDS -> DOUBLE-BUFFER at same 8 blocks/CU.
//     flush(t-1) reads bufX while compute(t) writes bufY: kills the LDS WAR
//     serialization, lets the scheduler spread the 24-store burst into the
//     serial v-chain's latency slots.

#define LL 8192
#define BB 32
#define FF 64
#define KK 8
#define CHUNK 128
#define NCH 64              // LL / CHUNK
#define WARM 96
#define NX (WARM + 7 + CHUNK)  // 231
#define TS 32               // timesteps per tile
#define NT (CHUNK / TS)     // 4
#define TSP (TS + 3)        // row stride 35 floats (odd -> <=2-way banks, free)

typedef float f32x4 __attribute__((ext_vector_type(4)));

__global__ __launch_bounds__(64) void snn_kernel(
    const float* __restrict__ x, const float* __restrict__ conv_w,
    const float* __restrict__ raw_tau, float* __restrict__ out)
{
    __shared__ float x_lds[NX + 1];        // 928 B
    __shared__ float vpA[FF][TSP];         // 8960 B  ([0]=carry vp_prev, [1..TS]=tile)
    __shared__ float vpB[FF][TSP];         // 8960 B
    __shared__ float alpha_s[FF];          // 256 B (per-feature alpha for flush rows)
    __shared__ float ioma_s[FF];           // 256 B (per-feature 1/(1-alpha))
                                           // total ~19.4 KB -> 8 blocks/CU

    const int f  = threadIdx.x;            // lane = feature
    const int b  = blockIdx.y;
    const int c  = blockIdx.x;
    const int t0 = c * CHUNK;
    const int g0 = t0 - WARM - 7;          // global time of x_lds[0]

    // ---- per-feature weights: unit-norm filter + alpha (fp64 setup) ----
    double wdd[KK];
    double ssum = 0.0;
    #pragma unroll
    for (int k = 0; k < KK; ++k) {
        double wv = (double)conv_w[f * KK + k];
        wdd[k] = wv;
        ssum += wv * wv;
    }
    double nrm = sqrt(ssum);
    if (nrm < 1e-8) nrm = 1e-8;
    double invn = 1.0 / nrm;
    float wf[KK];
    #pragma unroll
    for (int k = 0; k < KK; ++k) wf[k] = (float)(wdd[k] * invn);

    double rt     = (double)raw_tau[f];
    double tau    = log1p(exp(rt)) + 1e-4;  // softplus + eps
    double alphad = exp(-1.0 / tau);
    const float alpha = (float)alphad;
    const float oma   = (float)(1.0 - alphad);
    alpha_s[f] = alpha;
    ioma_s[f]  = (float)(1.0 / (1.0 - alphad));

    // ---- stage 20*x into LDS (zero pad for t<0) ----
    for (int i = f; i < NX; i += 64) {
        int g = g0 + i;
        x_lds[i] = (g >= 0) ? (20.0f * x[(size_t)b * LL + g]) : 0.0f;
    }
    // single-wave block: in-order DS pipe, no barrier needed.

    float* outI  = out;
    float* outZ  = out + (size_t)BB * FF * LL;
    float* outS  = out + (size_t)2 * BB * FF * LL;
    float* outLg = out + (size_t)3 * BB * FF * LL;

    float v = 0.0f, vp_last = 0.0f;

    // ---- warm-up ----
    #pragma unroll 8
    for (int s = 0; s < WARM; ++s) {
        float acc = 0.0f;
        #pragma unroll
        for (int k = 0; k < KK; ++k) acc = fmaf(wf[k], x_lds[s + k], acc);
        float vp = fmaf(alpha, v, oma * acc);
        vp_last = vp;
        v = (vp >= 0.25f) ? 0.0f : vp;
    }

    auto compute_tile = [&](int tile, float (*buf)[TSP]) {
        buf[f][0] = vp_last;               // carry: vp of step before tile start
        #pragma unroll
        for (int j = 0; j < TS; ++j) {
            int s = WARM + tile * TS + j;
            float acc = 0.0f;
            #pragma unroll
            for (int k = 0; k < KK; ++k) acc = fmaf(wf[k], x_lds[s + k], acc);
            float vp = fmaf(alpha, v, oma * acc);
            buf[f][j + 1] = vp;
            vp_last = vp;
            v = (vp >= 0.25f) ? 0.0f : vp;
        }
    };

    auto flush_tile = [&](int tile, float (*buf)[TSP]) {
        const int gt = t0 + tile * TS;
        const int r = f >> 3;              // row within group (0..7)
        const int q = (f & 7) * 4;         // time offset within tile
        #pragma unroll
        for (int it = 0; it < 8; ++it) {
            int fr = it * 8 + r;
            float al = alpha_s[fr];
            float io = ioma_s[fr];
            size_t base = ((size_t)b * FF + fr) * LL + gt + q;
            float p0 = buf[fr][q + 0];     // vp_{j-1} for first element
            float p1 = buf[fr][q + 1];
            float p2 = buf[fr][q + 2];
            float p3 = buf[fr][q + 3];
            float p4 = buf[fr][q + 4];
            f32x4 vi, vz, vs;
            {   // elem 0: vp=p1, vpm=p0
                float vprev = (p0 >= 0.25f) ? 0.0f : p0;
                vi.x = fmaf(-al, vprev, p1) * io;
                vz.x = fmaf(15.0f, p1, -3.75f);
                vs.x = (p1 >= 0.25f) ? 1.0f : 0.0f;
            }
            {   float vprev = (p1 >= 0.25f) ? 0.0f : p1;
                vi.y = fmaf(-al, vprev, p2) * io;
                vz.y = fmaf(15.0f, p2, -3.75f);
                vs.y = (p2 >= 0.25f) ? 1.0f : 0.0f;
            }
            {   float vprev = (p2 >= 0.25f) ? 0.0f : p2;
                vi.z = fmaf(-al, vprev, p3) * io;
                vz.z = fmaf(15.0f, p3, -3.75f);
                vs.z = (p3 >= 0.25f) ? 1.0f : 0.0f;
            }
            {   float vprev = (p3 >= 0.25f) ? 0.0f : p3;
                vi.w = fmaf(-al, vprev, p4) * io;
                vz.w = fmaf(15.0f, p4, -3.75f);
                vs.w = (p4 >= 0.25f) ? 1.0f : 0.0f;
            }
            __builtin_nontemporal_store(vi, reinterpret_cast<f32x4*>(outI + base));
            __builtin_nontemporal_store(vz, reinterpret_cast<f32x4*>(outZ + base));
            __builtin_nontemporal_store(vs, reinterpret_cast<f32x4*>(outS + base));
        }
        // logits: max over features (monotone: reduce vp, map once at the end)
        int t = f & 31, g = f >> 5;
        float m = buf[g * 32][t + 1];
        #pragma unroll
        for (int i = 1; i < 32; ++i) m = fmaxf(m, buf[g * 32 + i][t + 1]);
        m = fmaxf(m, __shfl_xor(m, 32));
        if (f < 32) outLg[(size_t)b * LL + gt + f] = fmaf(15.0f, m, -3.75f);
    };

    // software-pipelined: compute(t) overlaps flush(t-1) (disjoint buffers)
    compute_tile(0, vpA);
    #pragma unroll
    for (int tile = 1; tile < NT; ++tile) {
        if (tile & 1) { compute_tile(tile, vpB); flush_tile(tile - 1, vpA); }
        else          { compute_tile(tile, vpA); flush_tile(tile - 1, vpB); }
    }
    flush_tile(NT - 1, ((NT - 1) & 1) ? vpB : vpA);
}

extern "C" void kernel_launch(void* const* d_in, const int* in_sizes, int n_in,
                              void* d_out, int out_size, void* d_ws, size_t ws_size,
                              hipStream_t stream) {
    const float* x  = (const float*)d_in[0];
    const float* w  = (const float*)d_in[1];
    const float* rt = (const float*)d_in[2];
    float* out = (float*)d_out;
    dim3 grid(NCH, BB);
    snn_kernel<<<grid, 64, 0, stream>>>(x, w, rt, out);
}